// Round 3
// baseline (381.116 us; speedup 1.0000x reference)
//
#include <hip/hip_runtime.h>

// ---------------- problem constants ----------------
#define B_  128
#define N_  512
#define F_  128
#define L_  64
#define H_  128
#define C_  10

typedef short  bf8_t  __attribute__((ext_vector_type(8)));   // 8 x bf16 (MFMA A/B frag)
typedef float  f32x4  __attribute__((ext_vector_type(4)));   // MFMA C/D frag
typedef unsigned short us8 __attribute__((ext_vector_type(8)));

static __device__ __forceinline__ unsigned short f2bf(float x) {
    union { float f; unsigned u; } c; c.f = x;
    unsigned r = (c.u + 0x7fffu + ((c.u >> 16) & 1u)) >> 16;
    return (unsigned short)r;
}
static __device__ __forceinline__ float bf2f(unsigned short s) {
    union { unsigned u; float f; } c; c.u = ((unsigned)s) << 16;
    return c.f;
}
static __device__ __forceinline__ float elu(float x) { return x > 0.f ? x : expm1f(x); }

// ws offsets (float units) — every slot written before read inside one block
#define OFF_GBF   0           // 16777216 fl (33554432 bf16)  g as bf16
#define OFF_UBFT  16777216    // 2097152 fl (4194304 bf16)    u^T  [b][l][m]
#define OFF_H1Q   18874368    // 2097152 fl (4194304 bf16)    h1   [b][n][l]
#define OFF_KLP   20971520    // 128
#define OFF_MSEP  20971648    // 128
#define OFF_LP    20971776    // 128
#define OFF_COR   20971904    // 128

// LDS float offsets (12800 floats = 51.2 KB)
#define S_DEG   0      // [512]
#define S_TMU   512    // [512]            (P6: unused)
#define S_TLV   1024   // [512]            (P6: acts[128] reuse)
#define S_V     1536   // [512]
#define S_W     2048   // [512]
#define S_KL    2560   // [16]
#define S_MSE   2576   // [16]
#define S_LGS   2592   // [10]
#define S_HPS   2624   // [16*64]
#define S_HP    3648   // [64]
#define S_DEGP  512    // [16*512] P1 only (overlaps TMU..HPS — dead regions then)
#define S_WST   8704   // ushort[8192] = 4096 floats, XOR-swizzled W_s^T
#define S_TOT   12800

// One block per batch. 1024 threads = 16 waves. All deps block-local.
__global__ __launch_bounds__(1024) void kmega(
    const float* __restrict__ g, const float* __restrict__ h,
    const int* __restrict__ labels, const float* __restrict__ eps,
    const float* __restrict__ Ws, const float* __restrict__ b_s,
    const float* __restrict__ Wmu, const float* __restrict__ bmu,
    const float* __restrict__ Wlv, const float* __restrict__ blv,
    const float* __restrict__ Wdec, const float* __restrict__ bdec,
    const float* __restrict__ W1, const float* __restrict__ b1,
    const float* __restrict__ W2, const float* __restrict__ b2,
    const float* __restrict__ beta,
    unsigned short* __restrict__ gbf, unsigned short* __restrict__ ubfT,
    unsigned short* __restrict__ h1q,
    float* __restrict__ klp, float* __restrict__ msep_g,
    float* __restrict__ lp, float* __restrict__ cor)
{
    __shared__ float sm[S_TOT];
    const int b   = blockIdx.x;
    const int tid = threadIdx.x;
    const int w   = tid >> 6, lane = tid & 63;
    const int ml  = lane & 15, q = lane >> 4;

    // ---- P0: stage W_s^T bf16 [64][128] into LDS, XOR-swizzled (T2: break 16-way conflict) ----
    {
        unsigned short* wst = (unsigned short*)(sm + S_WST);
        for (int i = tid; i < F_ * L_; i += 1024) {
            int l = i >> 7, f = i & 127;
            wst[l * F_ + (f ^ ((l & 7) << 3))] = f2bf(Ws[f * L_ + l]);
        }
    }

    // ---- P1: g[b] -> bf16, per-wave column partials; reduce -> deg in LDS ----
    {
        const float*    gp = g   + ((size_t)b * N_ + w * 32) * N_ + lane * 8;
        unsigned short* gq = gbf + ((size_t)b * N_ + w * 32) * N_ + lane * 8;
        float cs[8] = {};
        #pragma unroll 4
        for (int r = 0; r < 32; ++r) {
            float4 v0 = *reinterpret_cast<const float4*>(gp + (size_t)r * N_);
            float4 v1 = *reinterpret_cast<const float4*>(gp + (size_t)r * N_ + 4);
            cs[0] += v0.x; cs[1] += v0.y; cs[2] += v0.z; cs[3] += v0.w;
            cs[4] += v1.x; cs[5] += v1.y; cs[6] += v1.z; cs[7] += v1.w;
            us8 qv;
            qv[0] = f2bf(v0.x); qv[1] = f2bf(v0.y); qv[2] = f2bf(v0.z); qv[3] = f2bf(v0.w);
            qv[4] = f2bf(v1.x); qv[5] = f2bf(v1.y); qv[6] = f2bf(v1.z); qv[7] = f2bf(v1.w);
            *reinterpret_cast<us8*>(gq + (size_t)r * N_) = qv;
        }
        #pragma unroll
        for (int j = 0; j < 8; ++j) sm[S_DEGP + w * 512 + lane * 8 + j] = cs[j];
    }
    __syncthreads();
    if (tid < 512) {
        float s = 0.f;
        #pragma unroll
        for (int k = 0; k < 16; ++k) s += sm[S_DEGP + k * 512 + tid];
        sm[S_DEG + tid] = s;
    }
    __syncthreads();

    // ---- P2: u^T[l][m] = (h[b]@Ws)^T / deg[m], MFMA with A=Ws^T (LDS), B=h rows ----
    {
        const unsigned short* wst = (const unsigned short*)(sm + S_WST);
        #pragma unroll
        for (int sub = 0; sub < 2; ++sub) {
            const int m0 = (2 * w + sub) * 16;
            const float* Bp = h + (size_t)(b * N_ + m0 + ml) * F_ + q * 8;
            f32x4 acc[4] = {};
            #pragma unroll
            for (int kk = 0; kk < F_; kk += 32) {
                float4 b0 = *reinterpret_cast<const float4*>(Bp + kk);
                float4 b1 = *reinterpret_cast<const float4*>(Bp + kk + 4);
                union { unsigned short s[8]; bf8_t v; } bv;
                bv.s[0] = f2bf(b0.x); bv.s[1] = f2bf(b0.y); bv.s[2] = f2bf(b0.z); bv.s[3] = f2bf(b0.w);
                bv.s[4] = f2bf(b1.x); bv.s[5] = f2bf(b1.y); bv.s[6] = f2bf(b1.z); bv.s[7] = f2bf(b1.w);
                #pragma unroll
                for (int i = 0; i < 4; ++i) {
                    const int l = i * 16 + ml;
                    bf8_t av = *reinterpret_cast<const bf8_t*>(
                        wst + l * F_ + ((q * 8 + kk) ^ ((ml & 7) << 3)));
                    acc[i] = __builtin_amdgcn_mfma_f32_16x16x32_bf16(av, bv.v, acc[i], 0, 0, 0);
                }
            }
            const float idg = 1.f / sm[S_DEG + m0 + ml];
            #pragma unroll
            for (int i = 0; i < 4; ++i) {
                #pragma unroll
                for (int r = 0; r < 4; ++r) {
                    int l = i * 16 + 4 * q + r;     // C row = A(Ws^T) row = l
                    ubfT[(size_t)(b * L_ + l) * N_ + m0 + ml] = f2bf(acc[i][r] * idg);
                }
            }
        }
    }
    __syncthreads();

    // ---- P3: h1 = ELU(gbf@u + b_s) via MFMA; fused tmu/tlv = (h1@Wmu|lv)/deg -> LDS ----
    {
        #pragma unroll
        for (int sub = 0; sub < 2; ++sub) {
            const int row0 = w * 32 + sub * 16;
            const unsigned short* A  = gbf  + (size_t)(b * N_ + row0 + ml) * N_ + q * 8;
            const unsigned short* B0 = ubfT + (size_t)(b * L_ + ml) * N_ + q * 8;
            f32x4 acc[4] = {};
            #pragma unroll 4
            for (int k = 0; k < N_; k += 32) {
                bf8_t a = *reinterpret_cast<const bf8_t*>(A + k);
                #pragma unroll
                for (int i = 0; i < 4; ++i) {
                    bf8_t bb = *reinterpret_cast<const bf8_t*>(B0 + (size_t)i * 16 * N_ + k);
                    acc[i] = __builtin_amdgcn_mfma_f32_16x16x32_bf16(a, bb, acc[i], 0, 0, 0);
                }
            }
            float bsv[4], wm[4], wl[4];
            #pragma unroll
            for (int i = 0; i < 4; ++i) {
                int col = i * 16 + ml;
                bsv[i] = b_s[col]; wm[i] = Wmu[col]; wl[i] = Wlv[col];
            }
            #pragma unroll
            for (int r = 0; r < 4; ++r) {
                int row = row0 + 4 * q + r;
                float pm = 0.f, pl = 0.f;
                #pragma unroll
                for (int i = 0; i < 4; ++i) {
                    float hv = elu(acc[i][r] + bsv[i]);
                    h1q[(size_t)(b * N_ + row) * L_ + i * 16 + ml] = f2bf(hv);
                    pm = fmaf(hv, wm[i], pm);
                    pl = fmaf(hv, wl[i], pl);
                }
                #pragma unroll
                for (int o = 1; o < 16; o <<= 1) { pm += __shfl_xor(pm, o); pl += __shfl_xor(pl, o); }
                if (ml == 0) {
                    float idg = 1.f / sm[S_DEG + row];
                    sm[S_TMU + row] = pm * idg;
                    sm[S_TLV + row] = pl * idg;
                }
            }
        }
    }
    __syncthreads();

    // ---- P4: amu/alv row-dots over gbf; mu/lv -> z -> v, w = v/deg; KL partial ----
    {
        const int n0 = w * 32;
        float tm[8], tl[8];
        *reinterpret_cast<float4*>(tm)     = *reinterpret_cast<const float4*>(sm + S_TMU + lane * 8);
        *reinterpret_cast<float4*>(tm + 4) = *reinterpret_cast<const float4*>(sm + S_TMU + lane * 8 + 4);
        *reinterpret_cast<float4*>(tl)     = *reinterpret_cast<const float4*>(sm + S_TLV + lane * 8);
        *reinterpret_cast<float4*>(tl + 4) = *reinterpret_cast<const float4*>(sm + S_TLV + lane * 8 + 4);

        const unsigned short* gbase = gbf + (size_t)(b * N_ + n0) * N_ + lane * 8;
        float myamu = 0.f, myalv = 0.f;
        #pragma unroll 4
        for (int r = 0; r < 32; ++r) {
            us8 gv = *reinterpret_cast<const us8*>(gbase + (size_t)r * N_);
            float amu = 0.f, alv = 0.f;
            #pragma unroll
            for (int j = 0; j < 8; ++j) {
                float gf = bf2f(gv[j]);
                amu = fmaf(gf, tm[j], amu);
                alv = fmaf(gf, tl[j], alv);
            }
            #pragma unroll
            for (int o = 32; o; o >>= 1) { amu += __shfl_xor(amu, o); alv += __shfl_xor(alv, o); }
            if (lane == r) { myamu = amu; myalv = alv; }
        }
        float klv = 0.f;
        if (lane < 32) {
            int n = n0 + lane;
            float mu = elu(myamu + bmu[0]);
            float lv = elu(myalv + blv[0]);
            float z  = mu + eps[b * N_ + n] * expf(0.5f * lv);
            float vs = 1.f / (1.f + expf(-beta[0] * z));
            sm[S_V + n] = vs;
            sm[S_W + n] = vs / sm[S_DEG + n];
            float e = expf(lv);
            klv = 1.f + 2.f * lv - mu * mu - e * e;
        }
        #pragma unroll
        for (int o = 32; o; o >>= 1) klv += __shfl_xor(klv, o);
        if (lane == 0) sm[S_KL + w] = klv;
    }
    __syncthreads();

    // ---- P5: p = gbf@w ; d = ELU(p*W_dec+b_dec); mse partial; hp partial ----
    {
        const int n0 = w * 32;
        const float wd = Wdec[lane], bd = bdec[lane];
        float wr[8];
        *reinterpret_cast<float4*>(wr)     = *reinterpret_cast<const float4*>(sm + S_W + lane * 8);
        *reinterpret_cast<float4*>(wr + 4) = *reinterpret_cast<const float4*>(sm + S_W + lane * 8 + 4);

        const unsigned short* gbase = gbf + (size_t)(b * N_ + n0) * N_ + lane * 8;
        float hpl = 0.f, msep = 0.f;
        #pragma unroll 2
        for (int t = 0; t < 32; ++t) {
            int n = n0 + t;
            us8 gv = *reinterpret_cast<const us8*>(gbase + (size_t)t * N_);
            float p = 0.f;
            #pragma unroll
            for (int j = 0; j < 8; ++j) p = fmaf(bf2f(gv[j]), wr[j], p);
            #pragma unroll
            for (int o = 32; o; o >>= 1) p += __shfl_xor(p, o);
            float dv  = elu(p * wd + bd);
            float h1v = bf2f(h1q[(size_t)(b * N_ + n) * L_ + lane]);
            float diff = h1v - dv;
            msep = fmaf(diff, diff, msep);
            hpl  = fmaf(h1v, sm[S_V + n], hpl);
        }
        sm[S_HPS + w * 64 + lane] = hpl;
        #pragma unroll
        for (int o = 32; o; o >>= 1) msep += __shfl_xor(msep, o);
        if (lane == 0) sm[S_MSE + w] = msep;
    }
    __syncthreads();

    // ---- P6: head for this batch ----
    if (tid < 64) {
        float s = 0.f;
        #pragma unroll
        for (int k = 0; k < 16; ++k) s += sm[S_HPS + k * 64 + tid];
        sm[S_HP + tid] = s;
    }
    __syncthreads();
    if (tid < H_) {
        float s0 = 0, s1 = 0, s2 = 0, s3 = 0;
        for (int l = 0; l < 64; l += 4) {
            s0 += sm[S_HP + l]     * W1[(l)     * H_ + tid];
            s1 += sm[S_HP + l + 1] * W1[(l + 1) * H_ + tid];
            s2 += sm[S_HP + l + 2] * W1[(l + 2) * H_ + tid];
            s3 += sm[S_HP + l + 3] * W1[(l + 3) * H_ + tid];
        }
        sm[S_TLV + tid] = elu((s0 + s1) + (s2 + s3) + b1[tid]);   // acts
    }
    __syncthreads();
    if (tid < C_) {
        float lg = b2[tid];
        for (int hh = 0; hh < H_; ++hh) lg += sm[S_TLV + hh] * W2[hh * C_ + tid];
        sm[S_LGS + tid] = lg;
    }
    __syncthreads();
    if (tid == 0) {
        float mx = sm[S_LGS]; int am = 0;
        for (int c = 1; c < C_; ++c) if (sm[S_LGS + c] > mx) { mx = sm[S_LGS + c]; am = c; }
        float se = 0.f;
        for (int c = 0; c < C_; ++c) se += expf(sm[S_LGS + c] - mx);
        int lbl = labels[b];
        lp[b]  = sm[S_LGS + lbl] - mx - logf(se);
        cor[b] = (am == lbl) ? 1.f : 0.f;
    }
    if (tid == 64) {
        float kk = 0.f;
        #pragma unroll
        for (int i = 0; i < 16; ++i) kk += sm[S_KL + i];
        klp[b] = kk;
    }
    if (tid == 65) {
        float mm = 0.f;
        #pragma unroll
        for (int i = 0; i < 16; ++i) mm += sm[S_MSE + i];
        msep_g[b] = mm;
    }
}

// ---------------- final reduce + loss ----------------
__global__ __launch_bounds__(128) void k7b_final(const float* __restrict__ lp, const float* __restrict__ cor,
                                                 const float* __restrict__ klp, const float* __restrict__ msep,
                                                 float* __restrict__ out) {
    __shared__ float r1[128], r2[128], r3[128], r4[128];
    int tid = threadIdx.x;
    r1[tid] = lp[tid]; r2[tid] = cor[tid]; r3[tid] = klp[tid]; r4[tid] = msep[tid];
    __syncthreads();
    for (int o = 64; o; o >>= 1) {
        if (tid < o) { r1[tid] += r1[tid + o]; r2[tid] += r2[tid + o];
                       r3[tid] += r3[tid + o]; r4[tid] += r4[tid + o]; }
        __syncthreads();
    }
    if (tid == 0) {
        float nll = -r1[0] / (float)B_;
        float kl  = r3[0] * (-0.5f / (65536.f * 65536.f));   // (-0.5/M)*(sum/M), M = B*N
        float mse = r4[0] / (float)(B_ * N_ * L_);
        out[0] = nll + kl + mse;
        out[1] = r2[0] / (float)B_;
    }
}

extern "C" void kernel_launch(void* const* d_in, const int* in_sizes, int n_in,
                              void* d_out, int out_size, void* d_ws, size_t ws_size,
                              hipStream_t stream) {
    const float* g     = (const float*)d_in[0];
    const float* h     = (const float*)d_in[1];
    const int*   labels= (const int*)  d_in[2];
    const float* eps   = (const float*)d_in[3];
    const float* Ws    = (const float*)d_in[4];
    const float* b_s   = (const float*)d_in[5];
    const float* Wmu   = (const float*)d_in[6];
    const float* bmu   = (const float*)d_in[7];
    const float* Wlv   = (const float*)d_in[8];
    const float* blv   = (const float*)d_in[9];
    const float* Wdec  = (const float*)d_in[10];
    const float* bdec  = (const float*)d_in[11];
    const float* W1    = (const float*)d_in[12];
    const float* b1    = (const float*)d_in[13];
    const float* W2    = (const float*)d_in[14];
    const float* b2    = (const float*)d_in[15];
    const float* beta  = (const float*)d_in[16];

    float* ws = (float*)d_ws;
    unsigned short* gbf  = (unsigned short*)(ws + OFF_GBF);
    unsigned short* ubfT = (unsigned short*)(ws + OFF_UBFT);
    unsigned short* h1q  = (unsigned short*)(ws + OFF_H1Q);
    float* klp  = ws + OFF_KLP;
    float* msep = ws + OFF_MSEP;
    float* lp   = ws + OFF_LP;
    float* cor  = ws + OFF_COR;

    kmega<<<B_, 1024, 0, stream>>>(g, h, labels, eps, Ws, b_s, Wmu, bmu, Wlv, blv,
                                   Wdec, bdec, W1, b1, W2, b2, beta,
                                   gbf, ubfT, h1q, klp, msep, lp, cor);
    k7b_final<<<1, 128, 0, stream>>>(lp, cor, klp, msep, (float*)d_out);
}

// Round 6
// 341.992 us; speedup vs baseline: 1.1144x; 1.1144x over previous
//
#include <hip/hip_runtime.h>

// ---------------- problem constants ----------------
#define B_  128
#define N_  512
#define F_  128
#define L_  64
#define H_  128
#define C_  10

typedef short  bf8_t  __attribute__((ext_vector_type(8)));   // 8 x bf16 (MFMA A/B frag)
typedef float  f32x4  __attribute__((ext_vector_type(4)));   // MFMA C/D frag
typedef unsigned short us8 __attribute__((ext_vector_type(8)));

static __device__ __forceinline__ unsigned short f2bf(float x) {
    union { float f; unsigned u; } c; c.f = x;
    unsigned r = (c.u + 0x7fffu + ((c.u >> 16) & 1u)) >> 16;
    return (unsigned short)r;
}
static __device__ __forceinline__ float bf2f(unsigned short s) {
    union { unsigned u; float f; } c; c.u = ((unsigned)s) << 16;
    return c.f;
}
static __device__ __forceinline__ float elu(float x) { return x > 0.f ? x : expm1f(x); }

// ws layout (float units) — no zero-init required anywhere
#define OFF_DEGP   0           // 2097152  deg partials [b][32][512]
#define OFF_DEG    2097152     // 65536
#define OFF_HPP    2162688     // 65536    hp partials [8][b][64]
#define OFF_KLP    2228224     // 1024     [b*8+c]
#define OFF_MSEP   2229248     // 1024     [b*8+c]
#define OFF_V      2230272     // 65536    v (f32)
#define OFF_LP     2295808     // 128
#define OFF_COR    2295936     // 128
#define OFF_TMUBF  2296064     // 32768    tmu bf16 [b][512]
#define OFF_TLVBF  2328832     // 32768    tlv bf16 [b][512]
#define OFF_WVBF   2361600     // 32768    w   bf16 [b][512]
#define OFF_H1Q    2394368     // 2097152  h1 bf16 [b][n][l]
#define OFF_GBF    4491520     // 16777216 g bf16 [b][n][m]
#define OFF_UBFT   21268736    // 2097152  u^T bf16 [b][l][m]
#define OFF_WSTBF  23365888    // 4096     W_s^T bf16

// ---------------- k1: g -> bf16 (us8 stores) + per-wave column-sum partials ----------------
// grid (8, B_), 256 thr = 4 waves; wave w owns rows [c8*64 + w*16, +16), lane owns 8 cols.
__global__ __launch_bounds__(256) void k1_deg(const float* __restrict__ g,
                                              const float* __restrict__ Ws,
                                              float* __restrict__ deg_part,
                                              unsigned short* __restrict__ gbf,
                                              unsigned short* __restrict__ WsTbf) {
    const int c8 = blockIdx.x, b = blockIdx.y;
    if (c8 == 0 && b == 0) {
        for (int i = threadIdx.x; i < F_ * L_; i += 256) {
            int l = i >> 7, f = i & 127;                 // dest [l][f]
            WsTbf[i] = f2bf(Ws[f * L_ + l]);
        }
    }
    const int w = threadIdx.x >> 6, lane = threadIdx.x & 63;
    const int r0 = c8 * 64 + w * 16;
    const float*    gp = g   + ((size_t)b * N_ + r0) * N_ + lane * 8;
    unsigned short* gq = gbf + ((size_t)b * N_ + r0) * N_ + lane * 8;
    float cs[8] = {};
    #pragma unroll 4
    for (int r = 0; r < 16; ++r) {
        float4 v0 = *reinterpret_cast<const float4*>(gp + (size_t)r * N_);
        float4 v1 = *reinterpret_cast<const float4*>(gp + (size_t)r * N_ + 4);
        cs[0] += v0.x; cs[1] += v0.y; cs[2] += v0.z; cs[3] += v0.w;
        cs[4] += v1.x; cs[5] += v1.y; cs[6] += v1.z; cs[7] += v1.w;
        us8 qv;
        qv[0] = f2bf(v0.x); qv[1] = f2bf(v0.y); qv[2] = f2bf(v0.z); qv[3] = f2bf(v0.w);
        qv[4] = f2bf(v1.x); qv[5] = f2bf(v1.y); qv[6] = f2bf(v1.z); qv[7] = f2bf(v1.w);
        *reinterpret_cast<us8*>(gq + (size_t)r * N_) = qv;
    }
    const int s = c8 * 4 + w;   // slice 0..31
    float* dp = deg_part + ((size_t)(b * 32 + s)) * N_ + lane * 8;
    *reinterpret_cast<float4*>(dp)     = make_float4(cs[0], cs[1], cs[2], cs[3]);
    *reinterpret_cast<float4*>(dp + 4) = make_float4(cs[4], cs[5], cs[6], cs[7]);
}

// ---------------- k2: finalize deg; u^T (bf16) = ((h @ W_s)/deg)^T via MFMA ----------------
__global__ __launch_bounds__(256) void k2_u(const float* __restrict__ h,
                                            const unsigned short* __restrict__ WsTbf,
                                            const float* __restrict__ deg_part,
                                            float* __restrict__ deg,
                                            unsigned short* __restrict__ ubfT) {
    __shared__ float tile[64 * 65];
    __shared__ float sdeg[64];
    const int b    = blockIdx.y;
    const int m0   = blockIdx.x * 64;
    const int tid  = threadIdx.x;
    const int wave = tid >> 6, lane = tid & 63;
    const int ml = lane & 15, q = lane >> 4;
    const int row0 = wave * 16;

    if (tid < 64) {
        int j = m0 + tid;
        float s = 0.f;
        #pragma unroll
        for (int k = 0; k < 32; ++k) s += deg_part[(size_t)(b * 32 + k) * N_ + j];
        sdeg[tid] = s;
        deg[b * N_ + j] = s;
    }

    const float* A = h + (size_t)(b * N_ + m0 + row0 + ml) * F_ + q * 8;
    const unsigned short* Bb = WsTbf + ml * F_ + q * 8;

    f32x4 acc[4] = {};
    #pragma unroll
    for (int kk = 0; kk < F_; kk += 32) {
        float4 a0 = *reinterpret_cast<const float4*>(A + kk);
        float4 a1 = *reinterpret_cast<const float4*>(A + kk + 4);
        union { unsigned short s[8]; bf8_t v; } av;
        av.s[0] = f2bf(a0.x); av.s[1] = f2bf(a0.y); av.s[2] = f2bf(a0.z); av.s[3] = f2bf(a0.w);
        av.s[4] = f2bf(a1.x); av.s[5] = f2bf(a1.y); av.s[6] = f2bf(a1.z); av.s[7] = f2bf(a1.w);
        #pragma unroll
        for (int i = 0; i < 4; ++i) {
            bf8_t bv = *reinterpret_cast<const bf8_t*>(Bb + i * 16 * F_ + kk);
            acc[i] = __builtin_amdgcn_mfma_f32_16x16x32_bf16(av.v, bv, acc[i], 0, 0, 0);
        }
    }
    __syncthreads();   // sdeg ready; tile not yet written
    #pragma unroll
    for (int i = 0; i < 4; ++i) {
        int col = i * 16 + ml;
        #pragma unroll
        for (int r = 0; r < 4; ++r) {
            int rl = row0 + 4 * q + r;
            tile[rl * 65 + col] = acc[i][r] / sdeg[rl];
        }
    }
    __syncthreads();
    for (int jj = 0; jj < 16; ++jj) {
        int ll = wave + jj * 4;
        ubfT[(size_t)(b * L_ + ll) * N_ + m0 + lane] = f2bf(tile[lane * 65 + ll]);
    }
}

// ---------------- k3: h1 = ELU(g@u + b_s) via MFMA; fused tmu/tlv (bf16) ----------------
__global__ __launch_bounds__(256) void k3_h1(const unsigned short* __restrict__ gbf,
                                             const unsigned short* __restrict__ ubfT,
                                             const float* __restrict__ b_s,
                                             const float* __restrict__ Wmu,
                                             const float* __restrict__ Wlv,
                                             const float* __restrict__ deg,
                                             unsigned short* __restrict__ h1q,
                                             unsigned short* __restrict__ tmubf,
                                             unsigned short* __restrict__ tlvbf) {
    const int b    = blockIdx.y;
    const int tid  = threadIdx.x;
    const int wave = tid >> 6, lane = tid & 63;
    const int row0 = blockIdx.x * 64 + wave * 16;
    const int ml = lane & 15, q = lane >> 4;

    const unsigned short* A  = gbf  + (size_t)(b * N_ + row0 + ml) * N_ + q * 8;
    const unsigned short* B0 = ubfT + (size_t)(b * L_ + ml) * N_ + q * 8;

    f32x4 acc[4] = {};
    #pragma unroll 4
    for (int k = 0; k < N_; k += 32) {
        bf8_t a = *reinterpret_cast<const bf8_t*>(A + k);
        #pragma unroll
        for (int i = 0; i < 4; ++i) {
            bf8_t bb = *reinterpret_cast<const bf8_t*>(B0 + (size_t)i * 16 * N_ + k);
            acc[i] = __builtin_amdgcn_mfma_f32_16x16x32_bf16(a, bb, acc[i], 0, 0, 0);
        }
    }
    float bsv[4], wm[4], wl[4];
    #pragma unroll
    for (int i = 0; i < 4; ++i) {
        int col = i * 16 + ml;
        bsv[i] = b_s[col]; wm[i] = Wmu[col]; wl[i] = Wlv[col];
    }
    #pragma unroll
    for (int r = 0; r < 4; ++r) {
        int row = row0 + 4 * q + r;
        float pm = 0.f, pl = 0.f;
        #pragma unroll
        for (int i = 0; i < 4; ++i) {
            float hv = elu(acc[i][r] + bsv[i]);
            h1q[(size_t)(b * N_ + row) * L_ + i * 16 + ml] = f2bf(hv);
            pm = fmaf(hv, wm[i], pm);
            pl = fmaf(hv, wl[i], pl);
        }
        #pragma unroll
        for (int o = 1; o < 16; o <<= 1) { pm += __shfl_xor(pm, o); pl += __shfl_xor(pl, o); }
        if (ml == 0) {
            float idg = 1.f / deg[b * N_ + row];
            tmubf[b * N_ + row] = f2bf(pm * idg);
            tlvbf[b * N_ + row] = f2bf(pl * idg);
        }
    }
}

// ---------------- k5: amu/alv via MFMA (B cols 0/1 = tmu/tlv); z -> v, w; KL partial ----------------
// grid (8, B_), 256 thr = 4 waves; wave handles 16 rows with one 16-MFMA chain.
__global__ __launch_bounds__(256) void k5_v(const unsigned short* __restrict__ gbf,
                                            const unsigned short* __restrict__ tmubf,
                                            const unsigned short* __restrict__ tlvbf,
                                            const float* __restrict__ eps, const float* __restrict__ deg,
                                            const float* __restrict__ bmu, const float* __restrict__ blv,
                                            const float* __restrict__ beta,
                                            float* __restrict__ vv, unsigned short* __restrict__ wvbf,
                                            float* __restrict__ kl_part) {
    __shared__ float kls[4];
    const int b = blockIdx.y;
    const int wave = threadIdx.x >> 6, lane = threadIdx.x & 63;
    const int ml = lane & 15, q = lane >> 4;
    const int n0 = (blockIdx.x * 4 + wave) * 16;

    const unsigned short* A  = gbf + (size_t)(b * N_ + n0 + ml) * N_ + q * 8;
    const unsigned short* Bp = ((ml & 1) ? tlvbf : tmubf) + (size_t)b * N_ + q * 8;

    f32x4 acc = {};
    #pragma unroll
    for (int k = 0; k < N_; k += 32) {
        bf8_t a  = *reinterpret_cast<const bf8_t*>(A + k);
        bf8_t bb = *reinterpret_cast<const bf8_t*>(Bp + k);
        acc = __builtin_amdgcn_mfma_f32_16x16x32_bf16(a, bb, acc, 0, 0, 0);
    }
    // C[m=4q+r][col=ml]: col0 = amu, col1 = alv
    float alv4[4];
    #pragma unroll
    for (int r = 0; r < 4; ++r) alv4[r] = __shfl_xor(acc[r], 1);

    float klv = 0.f;
    if (ml == 0) {
        const float bmu0 = bmu[0], blv0 = blv[0], beta0 = beta[0];
        #pragma unroll
        for (int r = 0; r < 4; ++r) {
            int n = n0 + 4 * q + r;
            float mu = elu(acc[r] + bmu0);
            float lv = elu(alv4[r] + blv0);
            float z  = mu + eps[b * N_ + n] * expf(0.5f * lv);
            float vs = 1.f / (1.f + expf(-beta0 * z));
            vv[b * N_ + n]   = vs;
            wvbf[b * N_ + n] = f2bf(vs / deg[b * N_ + n]);
            float e = expf(lv);
            klv += 1.f + 2.f * lv - mu * mu - e * e;
        }
    }
    klv += __shfl_xor(klv, 16);
    klv += __shfl_xor(klv, 32);
    if (lane == 0) kls[wave] = klv;
    __syncthreads();
    if (threadIdx.x == 0)
        kl_part[b * 8 + blockIdx.x] = kls[0] + kls[1] + kls[2] + kls[3];
}

// ---------------- k6: p = g@w via MFMA; d = ELU(p*W_dec+b_dec); mse + hp partials ----------------
// grid (8, B_), 256 thr = 4 waves; wave handles 16 rows.
__global__ __launch_bounds__(256) void k6_dec(const unsigned short* __restrict__ gbf,
                                              const unsigned short* __restrict__ wvbf,
                                              const float* __restrict__ vv,
                                              const unsigned short* __restrict__ h1q,
                                              const float* __restrict__ Wdec, const float* __restrict__ bdec,
                                              float* __restrict__ hp_part, float* __restrict__ mse_part) {
    __shared__ float hps[4 * 64];
    __shared__ float mses[4];
    const int b = blockIdx.y;
    const int tid = threadIdx.x, wave = tid >> 6, lane = tid & 63;
    const int ml = lane & 15, q = lane >> 4;
    const int n0 = (blockIdx.x * 4 + wave) * 16;

    const unsigned short* A  = gbf  + (size_t)(b * N_ + n0 + ml) * N_ + q * 8;
    const unsigned short* Bp = wvbf + (size_t)b * N_ + q * 8;

    f32x4 acc = {};
    #pragma unroll
    for (int k = 0; k < N_; k += 32) {
        bf8_t a  = *reinterpret_cast<const bf8_t*>(A + k);
        bf8_t bb = *reinterpret_cast<const bf8_t*>(Bp + k);
        acc = __builtin_amdgcn_mfma_f32_16x16x32_bf16(a, bb, acc, 0, 0, 0);
    }
    // p[m=4q+r] in col 0 (all cols equal); broadcast p_t from lane (t>>2)*16, reg t&3
    float pbc[16];
    #pragma unroll
    for (int t = 0; t < 16; ++t) pbc[t] = __shfl(acc[t & 3], (t >> 2) << 4);

    const float wd = Wdec[lane], bd = bdec[lane];
    float hpl = 0.f, msep = 0.f;
    #pragma unroll 4
    for (int t = 0; t < 16; ++t) {
        int n = n0 + t;
        float dv  = elu(pbc[t] * wd + bd);
        float h1v = bf2f(h1q[(size_t)(b * N_ + n) * L_ + lane]);
        float diff = h1v - dv;
        msep = fmaf(diff, diff, msep);
        hpl  = fmaf(h1v, vv[b * N_ + n], hpl);
    }
    hps[wave * 64 + lane] = hpl;
    #pragma unroll
    for (int o = 32; o; o >>= 1) msep += __shfl_xor(msep, o);
    if (lane == 0) mses[wave] = msep;
    __syncthreads();
    if (tid < 64) {
        float s = hps[tid] + hps[64 + tid] + hps[128 + tid] + hps[192 + tid];
        hp_part[(size_t)blockIdx.x * (B_ * 64) + b * 64 + tid] = s;
    }
    if (tid == 0)
        mse_part[b * 8 + blockIdx.x] = mses[0] + mses[1] + mses[2] + mses[3];
}

// ---------------- k7a: per-batch classifier head ----------------
__global__ __launch_bounds__(128) void k7a_head(const float* __restrict__ hp_part,
                                                const float* __restrict__ W1, const float* __restrict__ b1,
                                                const float* __restrict__ W2, const float* __restrict__ b2,
                                                const int* __restrict__ labels,
                                                float* __restrict__ lp, float* __restrict__ cor) {
    __shared__ float hps[64];
    __shared__ float acts[128];
    __shared__ float lgs[10];
    const int b = blockIdx.x, tid = threadIdx.x;
    if (tid < 64) {
        float s = 0.f;
        #pragma unroll
        for (int x = 0; x < 8; ++x) s += hp_part[(size_t)x * (B_ * 64) + b * 64 + tid];
        hps[tid] = s;
    }
    __syncthreads();
    float s0 = 0, s1 = 0, s2 = 0, s3 = 0;
    for (int l = 0; l < 64; l += 4) {
        s0 += hps[l]     * W1[(l)     * H_ + tid];
        s1 += hps[l + 1] * W1[(l + 1) * H_ + tid];
        s2 += hps[l + 2] * W1[(l + 2) * H_ + tid];
        s3 += hps[l + 3] * W1[(l + 3) * H_ + tid];
    }
    acts[tid] = elu((s0 + s1) + (s2 + s3) + b1[tid]);
    __syncthreads();
    if (tid < C_) {
        float lg = b2[tid];
        for (int hh = 0; hh < H_; ++hh) lg += acts[hh] * W2[hh * C_ + tid];
        lgs[tid] = lg;
    }
    __syncthreads();
    if (tid == 0) {
        float mx = lgs[0]; int am = 0;
        for (int c = 1; c < C_; ++c) if (lgs[c] > mx) { mx = lgs[c]; am = c; }
        float se = 0.f;
        for (int c = 0; c < C_; ++c) se += expf(lgs[c] - mx);
        int lbl = labels[b];
        lp[b]  = lgs[lbl] - mx - logf(se);
        cor[b] = (am == lbl) ? 1.f : 0.f;
    }
}

// ---------------- k7b: final reduce + loss ----------------
__global__ __launch_bounds__(128) void k7b_final(const float* __restrict__ lp, const float* __restrict__ cor,
                                                 const float* __restrict__ kl_part, const float* __restrict__ mse_part,
                                                 float* __restrict__ out) {
    __shared__ float r1[128], r2[128], r3[128], r4[128];
    int tid = threadIdx.x;
    r1[tid] = lp[tid]; r2[tid] = cor[tid];
    float k = 0.f, m = 0.f;
    #pragma unroll
    for (int i = 0; i < 8; ++i)  k += kl_part[tid + i * 128];
    #pragma unroll
    for (int i = 0; i < 8; ++i)  m += mse_part[tid + i * 128];
    r3[tid] = k; r4[tid] = m;
    __syncthreads();
    for (int o = 64; o; o >>= 1) {
        if (tid < o) { r1[tid] += r1[tid + o]; r2[tid] += r2[tid + o];
                       r3[tid] += r3[tid + o]; r4[tid] += r4[tid + o]; }
        __syncthreads();
    }
    if (tid == 0) {
        float nll = -r1[0] / (float)B_;
        float kl  = r3[0] * (-0.5f / (65536.f * 65536.f));   // (-0.5/M)*(sum/M), M = B*N
        float mse = r4[0] / (float)(B_ * N_ * L_);
        out[0] = nll + kl + mse;
        out[1] = r2[0] / (float)B_;
    }
}

extern "C" void kernel_launch(void* const* d_in, const int* in_sizes, int n_in,
                              void* d_out, int out_size, void* d_ws, size_t ws_size,
                              hipStream_t stream) {
    const float* g     = (const float*)d_in[0];
    const float* h     = (const float*)d_in[1];
    const int*   labels= (const int*)  d_in[2];
    const float* eps   = (const float*)d_in[3];
    const float* W_s   = (const float*)d_in[4];
    const float* b_s   = (const float*)d_in[5];
    const float* W_mu  = (const float*)d_in[6];
    const float* b_mu  = (const float*)d_in[7];
    const float* W_lv  = (const float*)d_in[8];
    const float* b_lv  = (const float*)d_in[9];
    const float* W_dec = (const float*)d_in[10];
    const float* b_dec = (const float*)d_in[11];
    const float* W1    = (const float*)d_in[12];
    const float* b1    = (const float*)d_in[13];
    const float* W2    = (const float*)d_in[14];
    const float* b2    = (const float*)d_in[15];
    const float* beta  = (const float*)d_in[16];

    float* ws = (float*)d_ws;
    float* deg_part = ws + OFF_DEGP;
    float* deg      = ws + OFF_DEG;
    float* hp_part  = ws + OFF_HPP;
    float* kl_part  = ws + OFF_KLP;
    float* mse_part = ws + OFF_MSEP;
    float* vv       = ws + OFF_V;
    float* lp       = ws + OFF_LP;
    float* cor      = ws + OFF_COR;
    unsigned short* tmubf = (unsigned short*)(ws + OFF_TMUBF);
    unsigned short* tlvbf = (unsigned short*)(ws + OFF_TLVBF);
    unsigned short* wvbf  = (unsigned short*)(ws + OFF_WVBF);
    unsigned short* h1q   = (unsigned short*)(ws + OFF_H1Q);
    unsigned short* gbf   = (unsigned short*)(ws + OFF_GBF);
    unsigned short* ubfT  = (unsigned short*)(ws + OFF_UBFT);
    unsigned short* WsTbf = (unsigned short*)(ws + OFF_WSTBF);

    k1_deg  <<<dim3(8, B_), 256, 0, stream>>>(g, W_s, deg_part, gbf, WsTbf);
    k2_u    <<<dim3(8, B_), 256, 0, stream>>>(h, WsTbf, deg_part, deg, ubfT);
    k3_h1   <<<dim3(8, B_), 256, 0, stream>>>(gbf, ubfT, b_s, W_mu, W_lv, deg, h1q, tmubf, tlvbf);
    k5_v    <<<dim3(8, B_), 256, 0, stream>>>(gbf, tmubf, tlvbf, eps, deg, b_mu, b_lv, beta, vv, wvbf, kl_part);
    k6_dec  <<<dim3(8, B_), 256, 0, stream>>>(gbf, wvbf, vv, h1q, W_dec, b_dec, hp_part, mse_part);
    k7a_head<<<B_, 128, 0, stream>>>(hp_part, W1, b1, W2, b2, labels, lp, cor);
    k7b_final<<<1, 128, 0, stream>>>(lp, cor, kl_part, mse_part, (float*)d_out);
}